// Round 7
// baseline (331.774 us; speedup 1.0000x reference)
//
#include <hip/hip_runtime.h>
#include <hip/hip_bf16.h>

#define NN 4096
#define KIN 256
#define HF 512
#define NHD 4
#define OF 128
#define JCH 128            // j per LDS chunk
#define NCH (NN / JCH)     // 32 chunks
#define VSTR 136           // vt stride (elements)
#define BSTR 132           // combine buffer stride (floats)

typedef __bf16 bf16x8 __attribute__((ext_vector_type(8)));
typedef __bf16 bf16x4 __attribute__((ext_vector_type(4)));
typedef float f32x4 __attribute__((ext_vector_type(4)));

// ---------------- K0: WT[c][k] = (bf16)W[k][c], LDS-tiled ----------------
__global__ __launch_bounds__(256) void k_transpose_w(const float* __restrict__ W,
                                                     __bf16* __restrict__ WT) {
    __shared__ __bf16 tl[64][65];
    int k0 = blockIdx.x * 64, c0 = blockIdx.y * 64;
    #pragma unroll
    for (int it = 0; it < 16; ++it) {
        int idx = it * 256 + threadIdx.x;
        int kk = idx >> 6, cc = idx & 63;
        tl[kk][cc] = (__bf16)W[(size_t)(k0 + kk) * HF + c0 + cc];
    }
    __syncthreads();
    #pragma unroll
    for (int it = 0; it < 16; ++it) {
        int idx = it * 256 + threadIdx.x;
        int cc = idx >> 6, kk = idx & 63;
        WT[(size_t)(c0 + cc) * KIN + k0 + kk] = tl[kk][cc];
    }
}

// ---------------- K1: hbT[c][m] = sum_k x[m][k]*W[k][c], 16x16x32 MFMA ------
__global__ __launch_bounds__(256) void k_gemm_h(const float* __restrict__ x,
                                                const __bf16* __restrict__ WT,
                                                __bf16* __restrict__ hbT) {
    int lane = threadIdx.x & 63, wave = threadIdx.x >> 6;
    int m = lane & 15, quad = lane >> 4;
    int m0 = blockIdx.x * 16;
    int c0 = blockIdx.y * 256 + wave * 64;
    f32x4 acc[4];
    #pragma unroll
    for (int nt = 0; nt < 4; ++nt) acc[nt] = (f32x4){0.f, 0.f, 0.f, 0.f};
    const float* xp = x + (size_t)(m0 + m) * KIN + quad * 8;
    #pragma unroll
    for (int kk = 0; kk < 8; ++kk) {
        float4 xa = *(const float4*)(xp + kk * 32);
        float4 xb = *(const float4*)(xp + kk * 32 + 4);
        bf16x8 af;
        af[0] = (__bf16)xa.x; af[1] = (__bf16)xa.y; af[2] = (__bf16)xa.z; af[3] = (__bf16)xa.w;
        af[4] = (__bf16)xb.x; af[5] = (__bf16)xb.y; af[6] = (__bf16)xb.z; af[7] = (__bf16)xb.w;
        #pragma unroll
        for (int nt = 0; nt < 4; ++nt) {
            bf16x8 bf = *(const bf16x8*)(WT + (size_t)(c0 + nt * 16 + m) * KIN + kk * 32 + quad * 8);
            acc[nt] = __builtin_amdgcn_mfma_f32_16x16x32_bf16(af, bf, acc[nt], 0, 0, 0);
        }
    }
    #pragma unroll
    for (int nt = 0; nt < 4; ++nt) {
        bf16x4 o;
        #pragma unroll
        for (int e = 0; e < 4; ++e) o[e] = (__bf16)acc[nt][e];
        *(bf16x4*)(hbT + (size_t)(c0 + nt * 16 + m) * NN + m0 + quad * 4) = o;
    }
}

// ---------------- K2: ci[h][n], cj[h][n] ----------------
__global__ __launch_bounds__(256) void k_cicj(const __bf16* __restrict__ hbT,
                                              const float* __restrict__ ai,
                                              const float* __restrict__ aj,
                                              float* __restrict__ ci,
                                              float* __restrict__ cj) {
    int h = threadIdx.x >> 6, lane = threadIdx.x & 63;
    int nl = lane & 15, fg = lane >> 4;
    int n = blockIdx.x * 16 + nl;
    float si = 0.f, sj = 0.f;
    for (int f0 = 0; f0 < 32; ++f0) {
        int c = h * OF + fg * 32 + f0;
        float v = (float)hbT[(size_t)c * NN + n];
        si += v * ai[c];
        sj += v * aj[c];
    }
    si += __shfl_xor(si, 16); si += __shfl_xor(si, 32);
    sj += __shfl_xor(sj, 16); sj += __shfl_xor(sj, 32);
    if (lane < 16) {
        ci[h * NN + n] = si;
        cj[h * NN + n] = sj;
    }
}

__device__ inline bf16x8 expblock(float4 A0, float4 A1, float civ,
                                  const float* cc, float& den) {
    float aa[8];
    aa[0] = A0.x; aa[1] = A0.y; aa[2] = A0.z; aa[3] = A0.w;
    aa[4] = A1.x; aa[5] = A1.y; aa[6] = A1.z; aa[7] = A1.w;
    bf16x8 af;
    #pragma unroll
    for (int u = 0; u < 8; ++u) {
        float a = aa[u];
        float s = civ + cc[u];
        s = fmaxf(s, s * 0.2f);     // leaky_relu
        s *= a;
        float p = __expf(s);        // s in ~[-4,4]: shift-free softmax safe
        den += p;
        af[u] = (__bf16)(p * a);
    }
    return af;
}

// ---------------- K3: fused attention -----------------------------------
// grid (128 i-tiles x 32 rows, 4 heads); block 256 = 4 waves.
// Wave w = j-quarter; all waves share LDS-staged V chunk (128 j), prefetched.
// Each wave: 2 row-groups (32 rows), 8 B-frags/chunk feed 16 MFMAs.
__global__ __launch_bounds__(256) void k_attn(const float* __restrict__ adj,
                                              const __bf16* __restrict__ hbT,
                                              const float* __restrict__ ci,
                                              const float* __restrict__ cj,
                                              const float* __restrict__ bias,
                                              float* __restrict__ out) {
    __shared__ __align__(16) char smem[OF * VSTR * 2 + 32 * BSTR * 4 + 4 * 2 * 16 * 4];
    __bf16* vt  = (__bf16*)smem;                          // [128][136]
    float* bufA = (float*)smem;                           // [32][132] aliases vt
    float* bufB = (float*)(smem + OF * VSTR * 2);         // [32][132]
    float* denp = (float*)(smem + OF * VSTR * 2 + 32 * BSTR * 4);  // [w][rg][16]

    int tid = threadIdx.x, lane = tid & 63, w = tid >> 6;
    int m = lane & 15, quad = lane >> 4;
    int hd = blockIdx.y, ibase = blockIdx.x * 32;
    float civ0 = ci[hd * NN + ibase + m];
    float civ1 = ci[hd * NN + ibase + 16 + m];
    const float* adj0 = adj + (size_t)(ibase + m) * NN + w * 32 + quad * 8;
    const float* adj1 = adj0 + (size_t)16 * NN;
    const float* cjp  = cj + hd * NN + w * 32 + quad * 8;
    // staging: thread -> f row = tid>>1, 64-j half = tid&1
    int fr = tid >> 1, hh = tid & 1;
    const __bf16* vsrc = hbT + (size_t)(hd * OF + fr) * NN + hh * 64;
    __bf16* vdst = vt + fr * VSTR + hh * 64;

    f32x4 acc[2][8];
    #pragma unroll
    for (int rg = 0; rg < 2; ++rg)
        #pragma unroll
        for (int nt = 0; nt < 8; ++nt) acc[rg][nt] = (f32x4){0.f, 0.f, 0.f, 0.f};
    float den0 = 0.f, den1 = 0.f;

    uint4 pre[8];
    #pragma unroll
    for (int k = 0; k < 8; ++k) pre[k] = *(const uint4*)(vsrc + k * 8);

    for (int c = 0; c < NCH; ++c) {
        int jo = c * JCH;
        // score operands for this chunk — issued before barriers (no vt dep)
        float4 a00 = *(const float4*)(adj0 + jo);
        float4 a01 = *(const float4*)(adj0 + jo + 4);
        float4 a10 = *(const float4*)(adj1 + jo);
        float4 a11 = *(const float4*)(adj1 + jo + 4);
        float4 cj0 = *(const float4*)(cjp + jo);
        float4 cj1 = *(const float4*)(cjp + jo + 4);
        __syncthreads();                    // vt consumed (prev chunk)
        #pragma unroll
        for (int k = 0; k < 8; ++k) *(uint4*)(vdst + k * 8) = pre[k];
        __syncthreads();                    // vt ready
        if (c + 1 < NCH) {
            #pragma unroll
            for (int k = 0; k < 8; ++k)
                pre[k] = *(const uint4*)(vsrc + (c + 1) * JCH + k * 8);
        }
        float cc[8];
        cc[0] = cj0.x; cc[1] = cj0.y; cc[2] = cj0.z; cc[3] = cj0.w;
        cc[4] = cj1.x; cc[5] = cj1.y; cc[6] = cj1.z; cc[7] = cj1.w;
        bf16x8 af0 = expblock(a00, a01, civ0, cc, den0);
        bf16x8 af1 = expblock(a10, a11, civ1, cc, den1);
        #pragma unroll
        for (int nt = 0; nt < 8; ++nt) {
            bf16x8 bf = *(const bf16x8*)(vt + (nt * 16 + m) * VSTR + w * 32 + quad * 8);
            acc[0][nt] = __builtin_amdgcn_mfma_f32_16x16x32_bf16(af0, bf, acc[0][nt], 0, 0, 0);
            acc[1][nt] = __builtin_amdgcn_mfma_f32_16x16x32_bf16(af1, bf, acc[1][nt], 0, 0, 0);
        }
    }
    // den per row-group: sum over quads (lane m holds row rg*16+m for this wave's j)
    den0 += __shfl_xor(den0, 16); den0 += __shfl_xor(den0, 32);
    den1 += __shfl_xor(den1, 16); den1 += __shfl_xor(den1, 32);
    if (lane < 16) {
        denp[w * 32 + 0 * 16 + lane] = den0;
        denp[w * 32 + 1 * 16 + lane] = den1;
    }
    __syncthreads();   // compute fully done; vt dead -> bufA reuse safe
    // combine tree over j-partials: w1->A, w3->B; w0+=A, w2+=B; w2->A; w0+=A
    if (w == 1 || w == 3) {
        float* b = (w == 1) ? bufA : bufB;
        #pragma unroll
        for (int rg = 0; rg < 2; ++rg)
            #pragma unroll
            for (int nt = 0; nt < 8; ++nt)
                #pragma unroll
                for (int reg = 0; reg < 4; ++reg)
                    b[(rg * 16 + quad * 4 + reg) * BSTR + nt * 16 + m] = acc[rg][nt][reg];
    }
    __syncthreads();
    if (w == 0 || w == 2) {
        float* b = (w == 0) ? bufA : bufB;
        #pragma unroll
        for (int rg = 0; rg < 2; ++rg)
            #pragma unroll
            for (int nt = 0; nt < 8; ++nt)
                #pragma unroll
                for (int reg = 0; reg < 4; ++reg)
                    acc[rg][nt][reg] += b[(rg * 16 + quad * 4 + reg) * BSTR + nt * 16 + m];
    }
    __syncthreads();
    if (w == 2) {
        #pragma unroll
        for (int rg = 0; rg < 2; ++rg)
            #pragma unroll
            for (int nt = 0; nt < 8; ++nt)
                #pragma unroll
                for (int reg = 0; reg < 4; ++reg)
                    bufA[(rg * 16 + quad * 4 + reg) * BSTR + nt * 16 + m] = acc[rg][nt][reg];
    }
    __syncthreads();
    if (w == 0) {
        #pragma unroll
        for (int rg = 0; rg < 2; ++rg)
            #pragma unroll
            for (int nt = 0; nt < 8; ++nt)
                #pragma unroll
                for (int reg = 0; reg < 4; ++reg)
                    acc[rg][nt][reg] += bufA[(rg * 16 + quad * 4 + reg) * BSTR + nt * 16 + m];
        // total den per row this lane stores: rows rg*16 + quad*4 + reg
        float dinv[2][4];
        #pragma unroll
        for (int rg = 0; rg < 2; ++rg)
            #pragma unroll
            for (int reg = 0; reg < 4; ++reg) {
                int r = rg * 16 + quad * 4 + reg;
                float dt = denp[0 * 32 + r] + denp[1 * 32 + r] +
                           denp[2 * 32 + r] + denp[3 * 32 + r];
                dinv[rg][reg] = 1.0f / dt;
            }
        #pragma unroll
        for (int nt = 0; nt < 8; ++nt) {
            float b = bias[hd * OF + nt * 16 + m];
            #pragma unroll
            for (int rg = 0; rg < 2; ++rg)
                #pragma unroll
                for (int reg = 0; reg < 4; ++reg) {
                    int i = ibase + rg * 16 + quad * 4 + reg;
                    out[(size_t)i * HF + hd * OF + nt * 16 + m] =
                        acc[rg][nt][reg] * dinv[rg][reg] + b;
                }
        }
    }
}

extern "C" void kernel_launch(void* const* d_in, const int* in_sizes, int n_in,
                              void* d_out, int out_size, void* d_ws, size_t ws_size,
                              hipStream_t stream) {
    const float* x    = (const float*)d_in[0];
    const float* adj  = (const float*)d_in[1];
    const float* W    = (const float*)d_in[2];
    const float* ai   = (const float*)d_in[3];
    const float* aj   = (const float*)d_in[4];
    const float* bias = (const float*)d_in[5];
    float* out = (float*)d_out;

    char* ws = (char*)d_ws;
    __bf16* WT  = (__bf16*)(ws);
    __bf16* hbT = (__bf16*)(ws + (1 << 18));
    float*  ci  = (float*)(ws + (1 << 18) + (1 << 22));
    float*  cj  = (float*)(ws + (1 << 18) + (1 << 22) + (1 << 16));

    k_transpose_w<<<dim3(4, 8), 256, 0, stream>>>(W, WT);
    k_gemm_h<<<dim3(256, 2), 256, 0, stream>>>(x, WT, hbT);
    k_cicj<<<256, 256, 0, stream>>>(hbT, ai, aj, ci, cj);
    k_attn<<<dim3(128, NHD), 256, 0, stream>>>(adj, hbT, ci, cj, bias, out);
}

// Round 8
// 277.725 us; speedup vs baseline: 1.1946x; 1.1946x over previous
//
#include <hip/hip_runtime.h>
#include <hip/hip_bf16.h>

#define NN 4096
#define KIN 256
#define HF 512
#define NHD 4
#define OF 128
#define JP 4160            // padded hbT row stride (8320 B: breaks 8KB channel aliasing)
#define VSTR 40            // vt j-stride (bf16): 80 B, 16B-aligned, uniform banks
#define ASTR 36            // at j-stride (f32): 144 B, 16B-aligned, uniform banks

typedef __bf16 bf16x8 __attribute__((ext_vector_type(8)));
typedef __bf16 bf16x4 __attribute__((ext_vector_type(4)));
typedef float f32x4 __attribute__((ext_vector_type(4)));
typedef _Float16 f16x4 __attribute__((ext_vector_type(4)));

// ---------------- K0: WT[c][k] = (bf16)W[k][c], LDS-tiled ----------------
__global__ __launch_bounds__(256) void k_transpose_w(const float* __restrict__ W,
                                                     __bf16* __restrict__ WT) {
    __shared__ __bf16 tl[64][65];
    int k0 = blockIdx.x * 64, c0 = blockIdx.y * 64;
    #pragma unroll
    for (int it = 0; it < 16; ++it) {
        int idx = it * 256 + threadIdx.x;
        int kk = idx >> 6, cc = idx & 63;
        tl[kk][cc] = (__bf16)W[(size_t)(k0 + kk) * HF + c0 + cc];
    }
    __syncthreads();
    #pragma unroll
    for (int it = 0; it < 16; ++it) {
        int idx = it * 256 + threadIdx.x;
        int cc = idx >> 6, kk = idx & 63;
        WT[(size_t)(c0 + cc) * KIN + k0 + kk] = tl[kk][cc];
    }
}

// ---------------- K1: hbT[c][m] (padded stride JP), 16x16x32 MFMA ------
__global__ __launch_bounds__(256) void k_gemm_h(const float* __restrict__ x,
                                                const __bf16* __restrict__ WT,
                                                __bf16* __restrict__ hbT) {
    int lane = threadIdx.x & 63, wave = threadIdx.x >> 6;
    int m = lane & 15, quad = lane >> 4;
    int m0 = blockIdx.x * 16;
    int c0 = blockIdx.y * 256 + wave * 64;
    f32x4 acc[4];
    #pragma unroll
    for (int nt = 0; nt < 4; ++nt) acc[nt] = (f32x4){0.f, 0.f, 0.f, 0.f};
    const float* xp = x + (size_t)(m0 + m) * KIN + quad * 8;
    #pragma unroll
    for (int kk = 0; kk < 8; ++kk) {
        float4 xa = *(const float4*)(xp + kk * 32);
        float4 xb = *(const float4*)(xp + kk * 32 + 4);
        bf16x8 af;
        af[0] = (__bf16)xa.x; af[1] = (__bf16)xa.y; af[2] = (__bf16)xa.z; af[3] = (__bf16)xa.w;
        af[4] = (__bf16)xb.x; af[5] = (__bf16)xb.y; af[6] = (__bf16)xb.z; af[7] = (__bf16)xb.w;
        #pragma unroll
        for (int nt = 0; nt < 4; ++nt) {
            bf16x8 bf = *(const bf16x8*)(WT + (size_t)(c0 + nt * 16 + m) * KIN + kk * 32 + quad * 8);
            acc[nt] = __builtin_amdgcn_mfma_f32_16x16x32_bf16(af, bf, acc[nt], 0, 0, 0);
        }
    }
    #pragma unroll
    for (int nt = 0; nt < 4; ++nt) {
        bf16x4 o;
        #pragma unroll
        for (int e = 0; e < 4; ++e) o[e] = (__bf16)acc[nt][e];
        *(bf16x4*)(hbT + (size_t)(c0 + nt * 16 + m) * JP + m0 + quad * 4) = o;
    }
}

// ---------------- K2: ci[h][n], cj[h][n] ----------------
__global__ __launch_bounds__(256) void k_cicj(const __bf16* __restrict__ hbT,
                                              const float* __restrict__ ai,
                                              const float* __restrict__ aj,
                                              float* __restrict__ ci,
                                              float* __restrict__ cj) {
    int h = threadIdx.x >> 6, lane = threadIdx.x & 63;
    int nl = lane & 15, fg = lane >> 4;
    int n = blockIdx.x * 16 + nl;
    float si = 0.f, sj = 0.f;
    for (int f0 = 0; f0 < 32; ++f0) {
        int c = h * OF + fg * 32 + f0;
        float v = (float)hbT[(size_t)c * JP + n];
        si += v * ai[c];
        sj += v * aj[c];
    }
    si += __shfl_xor(si, 16); si += __shfl_xor(si, 32);
    sj += __shfl_xor(sj, 16); sj += __shfl_xor(sj, 32);
    if (lane < 16) {
        ci[h * NN + n] = si;
        cj[h * NN + n] = sj;
    }
}

// ---------------- K3: fused attention, BM=64, js=4 ----------------
// grid 256 linear: js = bid&3 (XCD-pins V slice), i-tile = bid>>2 (64 rows).
// 512 thr = 8 waves = (head h = w&3, row-group rg = w>>2: 32 rows).
// Per 32-j chunk: adj tile (64x32 f32) + V tile (4h x 128f x 32j bf16) staged
// coalesced in LDS with register prefetch; 2 A-frags x 8 B-frags = 16 MFMA/wave.
__global__ __launch_bounds__(512, 2) void k_attn(const float* __restrict__ adj,
                                                 const __bf16* __restrict__ hbT,
                                                 const float* __restrict__ ci,
                                                 const float* __restrict__ cj,
                                                 _Float16* __restrict__ num,
                                                 float* __restrict__ den) {
    __shared__ __bf16 vt[NHD * OF * VSTR];   // [h][f][VSTR]  40 KB
    __shared__ float  at[64 * ASTR];         // [row][ASTR]   9.2 KB
    int tid = threadIdx.x, lane = tid & 63, w = tid >> 6;
    int h = w & 3, rg = w >> 2;
    int m = lane & 15, q = lane >> 4;
    int bid = blockIdx.x;
    int js = bid & 3, i0 = (bid >> 2) * 64, jb = js * 1024;

    // staging roles: V -> thread = one (h,f) row, 32 j (64 B); adj -> 8 thr/row
    int sh = tid >> 7, sf = tid & 127;
    const __bf16* vsrc = hbT + (size_t)(sh * OF + sf) * JP + jb;
    __bf16* vdst = vt + (sh * OF + sf) * VSTR;
    int ar = tid >> 3, as = tid & 7;
    const float* asrc = adj + (size_t)(i0 + ar) * NN + jb + as * 4;
    float* adst = at + ar * ASTR + as * 4;

    float civ0 = ci[h * NN + i0 + rg * 32 + m];
    float civ1 = ci[h * NN + i0 + rg * 32 + 16 + m];
    const float* cjp = cj + h * NN + jb + q * 8;

    f32x4 acc[2][8];
    #pragma unroll
    for (int rg2 = 0; rg2 < 2; ++rg2)
        #pragma unroll
        for (int nt = 0; nt < 8; ++nt) acc[rg2][nt] = (f32x4){0.f, 0.f, 0.f, 0.f};
    float den0 = 0.f, den1 = 0.f;

    uint4 vpre[4];
    float4 apre;
    #pragma unroll
    for (int k = 0; k < 4; ++k) vpre[k] = *(const uint4*)(vsrc + k * 8);
    apre = *(const float4*)(asrc);

    for (int c = 0; c < 32; ++c) {
        __syncthreads();                        // prev chunk consumed
        #pragma unroll
        for (int k = 0; k < 4; ++k) *(uint4*)(vdst + k * 8) = vpre[k];
        *(float4*)adst = apre;
        __syncthreads();                        // tiles ready
        if (c + 1 < 32) {                       // prefetch next chunk
            #pragma unroll
            for (int k = 0; k < 4; ++k)
                vpre[k] = *(const uint4*)(vsrc + (c + 1) * 32 + k * 8);
            apre = *(const float4*)(asrc + (c + 1) * 32);
        }
        float4 cj0 = *(const float4*)(cjp + c * 32);
        float4 cj1 = *(const float4*)(cjp + c * 32 + 4);
        float cc[8];
        cc[0] = cj0.x; cc[1] = cj0.y; cc[2] = cj0.z; cc[3] = cj0.w;
        cc[4] = cj1.x; cc[5] = cj1.y; cc[6] = cj1.z; cc[7] = cj1.w;
        // A-frags from at (fp32 adj, exact)
        const float* ap0 = at + (rg * 32 + m) * ASTR + q * 8;
        const float* ap1 = at + (rg * 32 + 16 + m) * ASTR + q * 8;
        float4 a00 = *(const float4*)(ap0), a01 = *(const float4*)(ap0 + 4);
        float4 a10 = *(const float4*)(ap1), a11 = *(const float4*)(ap1 + 4);
        float aa0[8], aa1[8];
        aa0[0] = a00.x; aa0[1] = a00.y; aa0[2] = a00.z; aa0[3] = a00.w;
        aa0[4] = a01.x; aa0[5] = a01.y; aa0[6] = a01.z; aa0[7] = a01.w;
        aa1[0] = a10.x; aa1[1] = a10.y; aa1[2] = a10.z; aa1[3] = a10.w;
        aa1[4] = a11.x; aa1[5] = a11.y; aa1[6] = a11.z; aa1[7] = a11.w;
        bf16x8 af0, af1;
        #pragma unroll
        for (int u = 0; u < 8; ++u) {
            float a = aa0[u];
            float s = civ0 + cc[u];
            s = fmaxf(s, s * 0.2f);
            s *= a;
            float p = __expf(s);
            den0 += p;
            af0[u] = (__bf16)(p * a);
        }
        #pragma unroll
        for (int u = 0; u < 8; ++u) {
            float a = aa1[u];
            float s = civ1 + cc[u];
            s = fmaxf(s, s * 0.2f);
            s *= a;
            float p = __expf(s);
            den1 += p;
            af1[u] = (__bf16)(p * a);
        }
        #pragma unroll
        for (int nt = 0; nt < 8; ++nt) {
            bf16x8 bf = *(const bf16x8*)(vt + (h * OF + nt * 16 + m) * VSTR + q * 8);
            acc[0][nt] = __builtin_amdgcn_mfma_f32_16x16x32_bf16(af0, bf, acc[0][nt], 0, 0, 0);
            acc[1][nt] = __builtin_amdgcn_mfma_f32_16x16x32_bf16(af1, bf, acc[1][nt], 0, 0, 0);
        }
    }
    // den: sum over q (j mod 32 partitions)
    den0 += __shfl_xor(den0, 16); den0 += __shfl_xor(den0, 32);
    den1 += __shfl_xor(den1, 16); den1 += __shfl_xor(den1, 32);
    if (lane < 16) {
        float* dp = den + ((size_t)js * NHD + h) * NN + i0 + rg * 32;
        dp[lane] = den0;
        dp[16 + lane] = den1;
    }
    // num partials (fp16): C/D row = q*4+reg, col = nt*16+m
    #pragma unroll
    for (int rg2 = 0; rg2 < 2; ++rg2)
        #pragma unroll
        for (int nt = 0; nt < 8; ++nt)
            #pragma unroll
            for (int reg = 0; reg < 4; ++reg) {
                int i = i0 + rg * 32 + rg2 * 16 + q * 4 + reg;
                num[((size_t)js * NN + i) * HF + h * OF + nt * 16 + m] =
                    (_Float16)acc[rg2][nt][reg];
            }
}

// ---------------- K4: reduce js partials, divide, +bias, fp32 out ---------
__global__ __launch_bounds__(256) void k_reduce(const _Float16* __restrict__ num,
                                                const float* __restrict__ den,
                                                const float* __restrict__ bias,
                                                float* __restrict__ out) {
    int g = blockIdx.x * 256 + threadIdx.x;    // NN*HF/4 groups
    int i = g >> 7, c4 = (g & 127) << 2;
    int h = c4 >> 7;
    float s0 = 0.f, s1 = 0.f, s2 = 0.f, s3 = 0.f, d = 0.f;
    #pragma unroll
    for (int js = 0; js < 4; ++js) {
        f16x4 v = *(const f16x4*)(num + ((size_t)js * NN + i) * HF + c4);
        s0 += (float)v[0]; s1 += (float)v[1]; s2 += (float)v[2]; s3 += (float)v[3];
        d += den[((size_t)js * NHD + h) * NN + i];
    }
    float inv = 1.0f / d;
    float4 b = *(const float4*)(bias + c4);
    float4 o;
    o.x = s0 * inv + b.x; o.y = s1 * inv + b.y;
    o.z = s2 * inv + b.z; o.w = s3 * inv + b.w;
    *(float4*)(out + (size_t)i * HF + c4) = o;
}

extern "C" void kernel_launch(void* const* d_in, const int* in_sizes, int n_in,
                              void* d_out, int out_size, void* d_ws, size_t ws_size,
                              hipStream_t stream) {
    const float* x    = (const float*)d_in[0];
    const float* adj  = (const float*)d_in[1];
    const float* W    = (const float*)d_in[2];
    const float* ai   = (const float*)d_in[3];
    const float* aj   = (const float*)d_in[4];
    const float* bias = (const float*)d_in[5];
    float* out = (float*)d_out;

    char* ws = (char*)d_ws;
    // ws: WT 256KB @21.0MB | hbT(padded) 4.26MB @0 | ci/cj 128KB | den 256KB | num(fp16) 16MB @5MB
    __bf16*   hbT = (__bf16*)(ws);                               // 4,259,840 B
    float*    ci  = (float*)(ws + 4358144);                      // 64 KB
    float*    cj  = (float*)(ws + 4358144 + 65536);              // 64 KB
    float*    den = (float*)(ws + 4358144 + 2 * 65536);          // 256 KB
    _Float16* num = (_Float16*)(ws + 5242880);                   // 16 MB -> ends 21 MB
    __bf16*   WT  = (__bf16*)(ws + 22020096);                    // 256 KB -> ends ~21.25 MB

    k_transpose_w<<<dim3(4, 8), 256, 0, stream>>>(W, WT);
    k_gemm_h<<<dim3(256, 2), 256, 0, stream>>>(x, WT, hbT);
    k_cicj<<<256, 256, 0, stream>>>(hbT, ai, aj, ci, cj);
    k_attn<<<256, 512, 0, stream>>>(adj, hbT, ci, cj, num, den);
    k_reduce<<<2048, 256, 0, stream>>>(num, den, bias, out);
}

// Round 9
// 218.388 us; speedup vs baseline: 1.5192x; 1.2717x over previous
//
#include <hip/hip_runtime.h>
#include <hip/hip_bf16.h>

#define NN 4096
#define KIN 256
#define HF 512
#define NHD 4
#define OF 128
#define JP 4160            // padded hbT row stride (8320 B: non-pow2 channel spread)
#define VSTR 72            // vt row stride (bf16): B-frag reads bank-uniform (free)
#define ASTR 68            // at row stride (f32): A-frag reads bank-uniform (free)

typedef __bf16 bf16x8 __attribute__((ext_vector_type(8)));
typedef __bf16 bf16x4 __attribute__((ext_vector_type(4)));
typedef float f32x4 __attribute__((ext_vector_type(4)));
typedef _Float16 f16x4 __attribute__((ext_vector_type(4)));

// ---------------- K0: WT[c][k] = (bf16)W[k][c], LDS-tiled ----------------
__global__ __launch_bounds__(256) void k_transpose_w(const float* __restrict__ W,
                                                     __bf16* __restrict__ WT) {
    __shared__ __bf16 tl[64][65];
    int k0 = blockIdx.x * 64, c0 = blockIdx.y * 64;
    #pragma unroll
    for (int it = 0; it < 16; ++it) {
        int idx = it * 256 + threadIdx.x;
        int kk = idx >> 6, cc = idx & 63;
        tl[kk][cc] = (__bf16)W[(size_t)(k0 + kk) * HF + c0 + cc];
    }
    __syncthreads();
    #pragma unroll
    for (int it = 0; it < 16; ++it) {
        int idx = it * 256 + threadIdx.x;
        int cc = idx >> 6, kk = idx & 63;
        WT[(size_t)(c0 + cc) * KIN + k0 + kk] = tl[kk][cc];
    }
}

// ------- K1: gemm (hbT) + fused ci/cj. Block = 16 nodes x all 512 c. -------
// 8 waves, wave w: c0 = w*64. A = x rows (node), B = WT rows (c).
__global__ __launch_bounds__(512) void k_gemm_h(const float* __restrict__ x,
                                                const __bf16* __restrict__ WT,
                                                const float* __restrict__ ai,
                                                const float* __restrict__ aj,
                                                __bf16* __restrict__ hbT,
                                                float* __restrict__ ci,
                                                float* __restrict__ cj) {
    __shared__ float credi[8][16], credj[8][16];
    int tid = threadIdx.x, lane = tid & 63, w = tid >> 6;
    int r = lane & 15, q = lane >> 4;
    int m0 = blockIdx.x * 16;
    int c0 = w * 64;
    f32x4 acc[4];
    #pragma unroll
    for (int nt = 0; nt < 4; ++nt) acc[nt] = (f32x4){0.f, 0.f, 0.f, 0.f};
    const float* xp = x + (size_t)(m0 + r) * KIN + q * 8;
    #pragma unroll
    for (int kk = 0; kk < 8; ++kk) {
        float4 xa = *(const float4*)(xp + kk * 32);
        float4 xb = *(const float4*)(xp + kk * 32 + 4);
        bf16x8 af;
        af[0] = (__bf16)xa.x; af[1] = (__bf16)xa.y; af[2] = (__bf16)xa.z; af[3] = (__bf16)xa.w;
        af[4] = (__bf16)xb.x; af[5] = (__bf16)xb.y; af[6] = (__bf16)xb.z; af[7] = (__bf16)xb.w;
        #pragma unroll
        for (int nt = 0; nt < 4; ++nt) {
            bf16x8 bf = *(const bf16x8*)(WT + (size_t)(c0 + nt * 16 + r) * KIN + kk * 32 + q * 8);
            acc[nt] = __builtin_amdgcn_mfma_f32_16x16x32_bf16(af, bf, acc[nt], 0, 0, 0);
        }
    }
    float pi[4] = {0.f, 0.f, 0.f, 0.f}, pj[4] = {0.f, 0.f, 0.f, 0.f};
    #pragma unroll
    for (int nt = 0; nt < 4; ++nt) {
        int c = c0 + nt * 16 + r;
        float av = ai[c], jv = aj[c];
        bf16x4 o;
        #pragma unroll
        for (int e = 0; e < 4; ++e) {
            o[e] = (__bf16)acc[nt][e];
            pi[e] += av * acc[nt][e];
            pj[e] += jv * acc[nt][e];
        }
        *(bf16x4*)(hbT + (size_t)c * JP + m0 + q * 4) = o;
    }
    #pragma unroll
    for (int off = 1; off < 16; off <<= 1)
        #pragma unroll
        for (int e = 0; e < 4; ++e) {
            pi[e] += __shfl_xor(pi[e], off);
            pj[e] += __shfl_xor(pj[e], off);
        }
    if (r == 0)
        #pragma unroll
        for (int e = 0; e < 4; ++e) {
            credi[w][q * 4 + e] = pi[e];
            credj[w][q * 4 + e] = pj[e];
        }
    __syncthreads();
    if (tid < 64) {                       // t = h*16 + node-local
        int h = tid >> 4, nl = tid & 15;
        ci[h * NN + m0 + nl] = credi[2 * h][nl] + credi[2 * h + 1][nl];
    } else if (tid < 128) {
        int t = tid - 64;
        int h = t >> 4, nl = t & 15;
        cj[h * NN + m0 + nl] = credj[2 * h][nl] + credj[2 * h + 1][nl];
    }
}

// ---------------- K3: fused attention, coalesced staging ----------------
// grid 256: js = bid&3 (XCD-pinned V slice), i-tile = bid>>2 (64 rows).
// 512 thr = 8 waves: h = w&3, rg = w>>2 (32 rows). 16 chunks of 64 j.
// Staging: 8 lanes cover one row's 128 B -> 8 tx/inst (was 64 per-lane-row).
__global__ __launch_bounds__(512, 2) void k_attn(const float* __restrict__ adj,
                                                 const __bf16* __restrict__ hbT,
                                                 const float* __restrict__ ci,
                                                 const float* __restrict__ cj,
                                                 _Float16* __restrict__ num,
                                                 float* __restrict__ den) {
    __shared__ __bf16 vt[NHD * OF * VSTR];   // 512 rows x 72 elts = 72 KB
    __shared__ float  at[64 * ASTR];         // 64 rows x 68 = 17 KB
    int tid = threadIdx.x, lane = tid & 63, w = tid >> 6;
    int h = w & 3, rg = w >> 2;
    int m = lane & 15, q = lane >> 4;
    int bid = blockIdx.x;
    int js = bid & 3, i0 = (bid >> 2) * 64, jb = js * 1024;

    // coalesced staging roles: row = tid>>3, 16B piece = tid&7
    int sr = tid >> 3, sc = tid & 7;
    const __bf16* vsrc = hbT + (size_t)sr * JP + jb + sc * 8;   // + p*64*JP + c*64
    const float*  asrc = adj + (size_t)(i0 + sr) * NN + jb + sc * 8;
    const float*  cjsrc = cj + h * NN + jb + q * 8;

    float civ0 = ci[h * NN + i0 + rg * 32 + m];
    float civ1 = ci[h * NN + i0 + rg * 32 + 16 + m];

    f32x4 acc[2][8];
    #pragma unroll
    for (int g = 0; g < 2; ++g)
        #pragma unroll
        for (int nt = 0; nt < 8; ++nt) acc[g][nt] = (f32x4){0.f, 0.f, 0.f, 0.f};
    float den0 = 0.f, den1 = 0.f;

    uint4 vpre[8];
    float4 apre0, apre1, cpre[4];
    #pragma unroll
    for (int p = 0; p < 8; ++p) vpre[p] = *(const uint4*)(vsrc + (size_t)p * 64 * JP);
    apre0 = *(const float4*)(asrc);
    apre1 = *(const float4*)(asrc + 4);
    cpre[0] = *(const float4*)(cjsrc);
    cpre[1] = *(const float4*)(cjsrc + 4);
    cpre[2] = *(const float4*)(cjsrc + 32);
    cpre[3] = *(const float4*)(cjsrc + 36);

    for (int c = 0; c < 16; ++c) {
        __syncthreads();                    // prev chunk consumed
        #pragma unroll
        for (int p = 0; p < 8; ++p)
            *(uint4*)(vt + (p * 64 + sr) * VSTR + sc * 8) = vpre[p];
        *(float4*)(at + sr * ASTR + sc * 8) = apre0;
        *(float4*)(at + sr * ASTR + sc * 8 + 4) = apre1;
        __syncthreads();                    // tiles ready
        float4 ca[4];
        #pragma unroll
        for (int e = 0; e < 4; ++e) ca[e] = cpre[e];
        if (c + 1 < 16) {                   // prefetch next chunk
            #pragma unroll
            for (int p = 0; p < 8; ++p)
                vpre[p] = *(const uint4*)(vsrc + (size_t)p * 64 * JP + (c + 1) * 64);
            apre0 = *(const float4*)(asrc + (c + 1) * 64);
            apre1 = *(const float4*)(asrc + (c + 1) * 64 + 4);
            cpre[0] = *(const float4*)(cjsrc + (c + 1) * 64);
            cpre[1] = *(const float4*)(cjsrc + (c + 1) * 64 + 4);
            cpre[2] = *(const float4*)(cjsrc + (c + 1) * 64 + 32);
            cpre[3] = *(const float4*)(cjsrc + (c + 1) * 64 + 36);
        }
        #pragma unroll
        for (int ks = 0; ks < 2; ++ks) {
            const float* a0 = at + (rg * 32 + m) * ASTR + ks * 32 + q * 8;
            const float* a1 = a0 + 16 * ASTR;
            float4 x00 = *(const float4*)(a0), x01 = *(const float4*)(a0 + 4);
            float4 x10 = *(const float4*)(a1), x11 = *(const float4*)(a1 + 4);
            float cc[8];
            cc[0] = ca[ks * 2].x; cc[1] = ca[ks * 2].y;
            cc[2] = ca[ks * 2].z; cc[3] = ca[ks * 2].w;
            cc[4] = ca[ks * 2 + 1].x; cc[5] = ca[ks * 2 + 1].y;
            cc[6] = ca[ks * 2 + 1].z; cc[7] = ca[ks * 2 + 1].w;
            float aa0[8], aa1[8];
            aa0[0] = x00.x; aa0[1] = x00.y; aa0[2] = x00.z; aa0[3] = x00.w;
            aa0[4] = x01.x; aa0[5] = x01.y; aa0[6] = x01.z; aa0[7] = x01.w;
            aa1[0] = x10.x; aa1[1] = x10.y; aa1[2] = x10.z; aa1[3] = x10.w;
            aa1[4] = x11.x; aa1[5] = x11.y; aa1[6] = x11.z; aa1[7] = x11.w;
            bf16x8 af0, af1;
            #pragma unroll
            for (int u = 0; u < 8; ++u) {
                float a = aa0[u];
                float s = civ0 + cc[u];
                s = fmaxf(s, s * 0.2f);     // leaky_relu
                s *= a;
                float p = __expf(s);        // s in ~[-4,4]: shift-free softmax safe
                den0 += p;
                af0[u] = (__bf16)(p * a);
            }
            #pragma unroll
            for (int u = 0; u < 8; ++u) {
                float a = aa1[u];
                float s = civ1 + cc[u];
                s = fmaxf(s, s * 0.2f);
                s *= a;
                float p = __expf(s);
                den1 += p;
                af1[u] = (__bf16)(p * a);
            }
            #pragma unroll
            for (int nt = 0; nt < 8; ++nt) {
                bf16x8 bf = *(const bf16x8*)(vt + (h * OF + nt * 16 + m) * VSTR + ks * 32 + q * 8);
                acc[0][nt] = __builtin_amdgcn_mfma_f32_16x16x32_bf16(af0, bf, acc[0][nt], 0, 0, 0);
                acc[1][nt] = __builtin_amdgcn_mfma_f32_16x16x32_bf16(af1, bf, acc[1][nt], 0, 0, 0);
            }
        }
    }
    // den over q-partitions (j mod 32): lanes {m, m+16, m+32, m+48}
    den0 += __shfl_xor(den0, 16); den0 += __shfl_xor(den0, 32);
    den1 += __shfl_xor(den1, 16); den1 += __shfl_xor(den1, 32);
    if (lane < 16) {
        float* dp = den + ((size_t)js * NHD + h) * NN + i0 + rg * 32;
        dp[lane] = den0;
        dp[16 + lane] = den1;
    }
    // num partials (fp16): C/D row = q*4+reg (i-local), col = nt*16+m (f)
    #pragma unroll
    for (int g = 0; g < 2; ++g)
        #pragma unroll
        for (int nt = 0; nt < 8; ++nt)
            #pragma unroll
            for (int reg = 0; reg < 4; ++reg) {
                int i = i0 + rg * 32 + g * 16 + q * 4 + reg;
                num[((size_t)js * NN + i) * HF + h * OF + nt * 16 + m] =
                    (_Float16)acc[g][nt][reg];
            }
}

// ---------------- K4: reduce js partials, divide, +bias, fp32 out ---------
__global__ __launch_bounds__(256) void k_reduce(const _Float16* __restrict__ num,
                                                const float* __restrict__ den,
                                                const float* __restrict__ bias,
                                                float* __restrict__ out) {
    int g = blockIdx.x * 256 + threadIdx.x;    // NN*HF/4 groups
    int i = g >> 7, c4 = (g & 127) << 2;
    int h = c4 >> 7;
    float s0 = 0.f, s1 = 0.f, s2 = 0.f, s3 = 0.f, d = 0.f;
    #pragma unroll
    for (int js = 0; js < 4; ++js) {
        f16x4 v = *(const f16x4*)(num + ((size_t)js * NN + i) * HF + c4);
        s0 += (float)v[0]; s1 += (float)v[1]; s2 += (float)v[2]; s3 += (float)v[3];
        d += den[((size_t)js * NHD + h) * NN + i];
    }
    float inv = 1.0f / d;
    float4 b = *(const float4*)(bias + c4);
    float4 o;
    o.x = s0 * inv + b.x; o.y = s1 * inv + b.y;
    o.z = s2 * inv + b.z; o.w = s3 * inv + b.w;
    *(float4*)(out + (size_t)i * HF + c4) = o;
}

extern "C" void kernel_launch(void* const* d_in, const int* in_sizes, int n_in,
                              void* d_out, int out_size, void* d_ws, size_t ws_size,
                              hipStream_t stream) {
    const float* x    = (const float*)d_in[0];
    const float* adj  = (const float*)d_in[1];
    const float* W    = (const float*)d_in[2];
    const float* ai   = (const float*)d_in[3];
    const float* aj   = (const float*)d_in[4];
    const float* bias = (const float*)d_in[5];
    float* out = (float*)d_out;

    char* ws = (char*)d_ws;
    __bf16*   hbT = (__bf16*)(ws);                       // 4,259,840 B
    float*    ci  = (float*)(ws + 4456448);              // 64 KB
    float*    cj  = (float*)(ws + 4456448 + 65536);      // 64 KB
    float*    den = (float*)(ws + 4587520);              // 256 KB
    __bf16*   WT  = (__bf16*)(ws + 4980736);             // 256 KB
    _Float16* num = (_Float16*)(ws + 5242880);           // 16 MB -> ends ~20.25 MB

    k_transpose_w<<<dim3(4, 8), 256, 0, stream>>>(W, WT);
    k_gemm_h<<<256, 512, 0, stream>>>(x, WT, ai, aj, hbT, ci, cj);
    k_attn<<<256, 512, 0, stream>>>(adj, hbT, ci, cj, num, den);
    k_reduce<<<2048, 256, 0, stream>>>(num, den, bias, out);
}